// Round 1
// baseline (808.645 us; speedup 1.0000x reference)
//
#include <hip/hip_runtime.h>
#include <math.h>

#define PHI_F     1.618033988749895f
#define LUT_N     4096
#define LUT_INV   651.8986469044033f      /* 4096/(2*pi) rounded to f32 */
#define LUT_STEP  0.0015339807878856412f  /* 2*pi/4096  rounded to f32 */

#define B_  8
#define S_  512
#define D_  64
#define H_  4
#define DH_ 16
#define N_  128
#define V_  32000
#define R_  (B_ * S_)   /* 4096 rows */

// ---------------------------------------------------------------- LUT interp
__device__ __forceinline__ void lut_sc(const float* __restrict__ sL,
                                       const float* __restrict__ cL,
                                       float th, float& s, float& c) {
    float pos = th * LUT_INV;
    float f0  = floorf(pos);
    float fr  = pos - f0;
    int   i0  = ((int)f0) & (LUT_N - 1);
    int   i1  = (i0 + 1) & (LUT_N - 1);
    float om  = 1.0f - fr;
    s = sL[i0] * om + sL[i1] * fr;
    c = cL[i0] * om + cL[i1] * fr;
}

// ---------------------------------------------------------------- table build
__global__ void k_tables(float* __restrict__ sT, float* __restrict__ cT) {
    int i = blockIdx.x * blockDim.x + threadIdx.x;
    if (i < LUT_N) {
        float g = (float)i * LUT_STEP;        // matches np.arange(f32) * (2pi/4096)
        sT[i] = (float)sin((double)g);
        cT[i] = (float)cos((double)g);
    }
}

// ---------------------------------------------------------------- scan
// 8 blocks (one per b) x 64 threads (one per d). Sequential over t.
__global__ __launch_bounds__(64) void k_scan(const int* __restrict__ ids,
                                             const float* __restrict__ emb,
                                             const float* __restrict__ sT,
                                             const float* __restrict__ cT,
                                             float* __restrict__ states) {
    __shared__ float sL[LUT_N], cL[LUT_N];
    int d = threadIdx.x;
    int b = blockIdx.x;
    for (int i = d; i < LUT_N; i += 64) { sL[i] = sT[i]; cL[i] = cT[i]; }
    __syncthreads();
    float hr = 0.0f, hi = 0.0f;
    for (int t = 0; t < S_; ++t) {
        int   id = ids[b * S_ + t];
        float w  = emb[id * (2 * D_) + d];
        float bt = emb[id * (2 * D_) + D_ + d];
        float wl = 1.0f + fabsf(w);
        float tp = (float)t * PHI_F;
        float thr = hr / wl + bt + tp;
        float thi = hi / wl + bt + tp;
        float sr, cr, si, ci;
        lut_sc(sL, cL, thr, sr, cr);
        lut_sc(sL, cL, thi, si, ci);
        float nr = cr * ci - sr * si;
        float ni = cr * si + sr * ci;
        hr = nr; hi = ni;
        states[(b * S_ + t) * D_ + d] = nr + ni;
    }
}

// ---------------------------------------------------------------- q/k build
__global__ __launch_bounds__(256) void k_qk(const float* __restrict__ states,
                                            const float* __restrict__ wq,
                                            const float* __restrict__ bq,
                                            const float* __restrict__ wk,
                                            const float* __restrict__ bk,
                                            const float* __restrict__ sT,
                                            const float* __restrict__ cT,
                                            float* __restrict__ q,
                                            float* __restrict__ k) {
    __shared__ float sL[LUT_N], cL[LUT_N];
    for (int i = threadIdx.x; i < LUT_N; i += 256) { sL[i] = sT[i]; cL[i] = cT[i]; }
    __syncthreads();
    const int total = R_ * H_ * DH_;   // 262144
    for (int idx = blockIdx.x * 256 + threadIdx.x; idx < total; idx += gridDim.x * 256) {
        int j  = idx & (DH_ - 1);
        int h  = (idx >> 4) & (H_ - 1);
        int bt = idx >> 6;
        int t  = bt & (S_ - 1);
        float xp = states[idx];               // layout matches (bt*64 + h*16 + j)
        float tp = (float)t * PHI_F;
        int   hj = h * DH_ + j;
        float thq = xp / (1.0f + fabsf(wq[hj])) + bq[hj] + tp;
        float thk = xp / (1.0f + fabsf(wk[hj])) + bk[hj];
        float sq, cq, sk, ck;
        lut_sc(sL, cL, thq, sq, cq);
        lut_sc(sL, cL, thk, sk, ck);
        int base = bt * (H_ * 2 * DH_) + h * (2 * DH_) + j;
        q[base] = cq; q[base + DH_] = sq;
        k[base] = ck; k[base + DH_] = sk;
    }
}

// ---------------------------------------------------------------- attention
// Block per (b,t), 256 threads = 4 waves, wave h handles head h.
__global__ __launch_bounds__(256) void k_attn(const float* __restrict__ states,
                                              const float* __restrict__ q,
                                              const float* __restrict__ k,
                                              const float* __restrict__ wctx,
                                              float* __restrict__ x) {
    int bt = blockIdx.x;
    int b  = bt >> 9, t = bt & (S_ - 1);
    int tid = threadIdx.x;
    if (t == 0) {                       // has_ctx == 0 at t==0
        if (tid < D_) x[bt * D_ + tid] = states[bt * D_ + tid];
        return;
    }
    __shared__ float wlds[H_][S_];
    __shared__ float ql[H_][2 * DH_];
    __shared__ float cpart[4][D_];
    int h = tid >> 6, l = tid & 63;
    if (l < 2 * DH_) ql[h][l] = q[bt * 128 + h * 32 + l];
    __syncthreads();

    const float* kb = k + (size_t)(b * S_) * 128 + h * 32;
    float sc[8];
    float m = -INFINITY;
#pragma unroll
    for (int jj = 0; jj < 8; ++jj) {
        int s = l + jj * 64;
        float v = -INFINITY;
        if (s < t) {
            const float4* kp = (const float4*)(kb + (size_t)s * 128);
            float acc = 0.0f;
#pragma unroll
            for (int c = 0; c < 8; ++c) {
                float4 kv = kp[c];
                acc += kv.x * ql[h][c * 4 + 0] + kv.y * ql[h][c * 4 + 1]
                     + kv.z * ql[h][c * 4 + 2] + kv.w * ql[h][c * 4 + 3];
            }
            v = acc * 0.1767766952966369f;   // 1/sqrt(2*dh)
            m = fmaxf(m, v);
        }
        sc[jj] = v;
    }
    for (int o = 32; o; o >>= 1) m = fmaxf(m, __shfl_xor(m, o));
    float sum = 0.0f;
#pragma unroll
    for (int jj = 0; jj < 8; ++jj) {
        float e = expf(sc[jj] - m);      // expf(-inf)=0 handles the mask
        sc[jj] = e; sum += e;
    }
    for (int o = 32; o; o >>= 1) sum += __shfl_xor(sum, o);
    float inv = 1.0f / sum;
#pragma unroll
    for (int jj = 0; jj < 8; ++jj) {
        int s = l + jj * 64;
        if (s < S_) wlds[h][s] = sc[jj] * inv;
    }
    __syncthreads();
    // context: lane d, wave p strides over s
    {
        int d = tid & 63, p = tid >> 6;
        float acc = 0.0f;
        for (int s = p; s < t; s += 4) {
            float w4 = wlds[0][s] + wlds[1][s] + wlds[2][s] + wlds[3][s];
            acc += w4 * states[((size_t)b * S_ + s) * D_ + d];
        }
        cpart[p][d] = acc;
    }
    __syncthreads();
    if (tid < D_) {
        float c = cpart[0][tid] + cpart[1][tid] + cpart[2][tid] + cpart[3][tid];
        cpart[0][tid] = c;
    }
    __syncthreads();
    if (tid < D_) {
        float y = 0.0f;
        const float* wr = wctx + tid * D_;
        for (int d = 0; d < D_; ++d) y += cpart[0][d] * wr[d];
        x[bt * D_ + tid] = states[bt * D_ + tid] + y;
    }
}

// ---------------------------------------------------------------- residual phase block
// 512 blocks x 256 threads, 8 (b,t)-rows per block. thread: n = tid>>1, half of d.
__global__ __launch_bounds__(256) void k_resid(float* __restrict__ x,
                                               const float* __restrict__ Wres,
                                               const float* __restrict__ Bres,
                                               const float* __restrict__ wpr,
                                               const float* __restrict__ wpi,
                                               const float* __restrict__ sT,
                                               const float* __restrict__ cT) {
    __shared__ float sL[LUT_N], cL[LUT_N];
    __shared__ float xv[D_];
    __shared__ float csum[N_], ssum[N_];
    int tid = threadIdx.x;
    for (int i = tid; i < LUT_N; i += 256) { sL[i] = sT[i]; cL[i] = cT[i]; }
    int n  = tid >> 1;
    int d0 = (tid & 1) * 32;
    for (int r = 0; r < 8; ++r) {
        int bt = blockIdx.x * 8 + r;
        int t  = bt & (S_ - 1);
        float tp = (float)t * PHI_F;
        __syncthreads();
        if (tid < D_) xv[tid] = x[bt * D_ + tid];
        __syncthreads();
        float cs = 0.0f, ss = 0.0f;
#pragma unroll
        for (int dd = 0; dd < 32; ++dd) {
            int d  = d0 + dd;
            int nd = n * D_ + d;
            float th = xv[d] / (1.0f + fabsf(Wres[nd])) + Bres[nd] + tp;
            float s, c;
            lut_sc(sL, cL, th, s, c);
            cs += c; ss += s;
        }
        cs += __shfl_xor(cs, 1);
        ss += __shfl_xor(ss, 1);
        if ((tid & 1) == 0) { csum[n] = cs; ssum[n] = ss; }
        __syncthreads();
        if (tid < D_) {
            float pre = 0.0f;
            const float* pr = wpr + tid * N_;
            const float* pi = wpi + tid * N_;
            for (int nn = 0; nn < N_; ++nn) pre += csum[nn] * pr[nn] + ssum[nn] * pi[nn];
            float sig = 1.0f / (1.0f + expf(-pre));
            x[bt * D_ + tid] = xv[tid] + pre * sig;
        }
    }
}

// ---------------------------------------------------------------- output GEMM (fp32)
// out[r,v] = sum_d x[r,d] * wout[v,d]. Tile 64x64, thread micro-tile 4x4.
__global__ __launch_bounds__(256) void k_out(const float* __restrict__ x,
                                             const float* __restrict__ wout,
                                             float* __restrict__ out) {
    __shared__ float xsT[D_][65];   // [k][row]
    __shared__ float wsT[D_][65];   // [k][col]
    int tid = threadIdx.x;
    int cbase = blockIdx.x * 64;
    int rbase = blockIdx.y * 64;
    for (int i = tid; i < 64 * 64; i += 256) {
        int row = i >> 6, d = i & 63;
        xsT[d][row] = x[(size_t)(rbase + row) * D_ + d];
        wsT[d][row] = wout[(size_t)(cbase + row) * D_ + d];   // "row" is col here
    }
    __syncthreads();
    int tc = tid & 15, tr = tid >> 4;
    float acc[4][4];
#pragma unroll
    for (int i = 0; i < 4; ++i)
#pragma unroll
        for (int j = 0; j < 4; ++j) acc[i][j] = 0.0f;
#pragma unroll 8
    for (int kk = 0; kk < D_; ++kk) {
        float4 xv = *(const float4*)&xsT[kk][tr * 4];
        float4 wv = *(const float4*)&wsT[kk][tc * 4];
        float xa[4] = {xv.x, xv.y, xv.z, xv.w};
        float wa[4] = {wv.x, wv.y, wv.z, wv.w};
#pragma unroll
        for (int i = 0; i < 4; ++i)
#pragma unroll
            for (int j = 0; j < 4; ++j) acc[i][j] += xa[i] * wa[j];
    }
#pragma unroll
    for (int i = 0; i < 4; ++i) {
        float4 o = make_float4(acc[i][0], acc[i][1], acc[i][2], acc[i][3]);
        *(float4*)&out[(size_t)(rbase + tr * 4 + i) * V_ + cbase + tc * 4] = o;
    }
}

// ---------------------------------------------------------------- launcher
extern "C" void kernel_launch(void* const* d_in, const int* in_sizes, int n_in,
                              void* d_out, int out_size, void* d_ws, size_t ws_size,
                              hipStream_t stream) {
    const int*   ids  = (const int*)  d_in[0];
    const float* emb  = (const float*)d_in[1];
    const float* wq   = (const float*)d_in[2];
    const float* bq   = (const float*)d_in[3];
    const float* wk   = (const float*)d_in[4];
    const float* bk   = (const float*)d_in[5];
    const float* wctx = (const float*)d_in[6];
    const float* Wres = (const float*)d_in[7];
    const float* Bres = (const float*)d_in[8];
    const float* wpr  = (const float*)d_in[9];
    const float* wpi  = (const float*)d_in[10];
    const float* wout = (const float*)d_in[11];
    float* out = (float*)d_out;

    float* sT     = (float*)d_ws;                 // 4096
    float* cT     = sT + LUT_N;                   // 4096
    float* states = cT + LUT_N;                   // 262144
    float* qbuf   = states + R_ * D_;             // 524288
    float* kbuf   = qbuf + R_ * H_ * 2 * DH_;     // 524288
    float* xbuf   = kbuf + R_ * H_ * 2 * DH_;     // 262144

    k_tables<<<16, 256, 0, stream>>>(sT, cT);
    k_scan  <<<B_, 64, 0, stream>>>(ids, emb, sT, cT, states);
    k_qk    <<<64, 256, 0, stream>>>(states, wq, bq, wk, bk, sT, cT, qbuf, kbuf);
    k_attn  <<<R_, 256, 0, stream>>>(states, qbuf, kbuf, wctx, xbuf);
    k_resid <<<R_ / 8, 256, 0, stream>>>(xbuf, Wres, Bres, wpr, wpi, sT, cT);
    k_out   <<<dim3(V_ / 64, R_ / 64), 256, 0, stream>>>(xbuf, wout, out);
}

// Round 2
// 635.994 us; speedup vs baseline: 1.2715x; 1.2715x over previous
//
#include <hip/hip_runtime.h>
#include <hip/hip_bf16.h>
#include <math.h>

#define PHI_F     1.618033988749895f
#define LUT_N     4096
#define LUT_INV   651.8986469044033f      /* 4096/(2*pi) rounded to f32 */
#define LUT_STEP  0.0015339807878856412f  /* 2*pi/4096  rounded to f32 */

#define B_  8
#define S_  512
#define D_  64
#define H_  4
#define DH_ 16
#define N_  128
#define V_  32000
#define R_  (B_ * S_)   /* 4096 rows */

typedef __attribute__((ext_vector_type(8))) short short8_t;
typedef __attribute__((ext_vector_type(4))) float f32x4;

// ---------------------------------------------------------------- LUT interp
__device__ __forceinline__ void lut_sc(const float* __restrict__ sL,
                                       const float* __restrict__ cL,
                                       float th, float& s, float& c) {
    float pos = th * LUT_INV;
    float f0  = floorf(pos);
    float fr  = pos - f0;
    int   i0  = ((int)f0) & (LUT_N - 1);
    int   i1  = (i0 + 1) & (LUT_N - 1);
    float om  = 1.0f - fr;
    s = sL[i0] * om + sL[i1] * fr;
    c = cL[i0] * om + cL[i1] * fr;
}

// ---------------------------------------------------------------- table build
__global__ void k_tables(float* __restrict__ sT, float* __restrict__ cT) {
    int i = blockIdx.x * blockDim.x + threadIdx.x;
    if (i < LUT_N) {
        float g = (float)i * LUT_STEP;        // matches np.arange(f32) * (2pi/4096)
        sT[i] = (float)sin((double)g);
        cT[i] = (float)cos((double)g);
    }
}

// ---------------------------------------------------------------- wout -> bf16
__global__ __launch_bounds__(256) void k_cvt(const float* __restrict__ w,
                                             __hip_bfloat16* __restrict__ wb,
                                             int n4) {
    int i = blockIdx.x * 256 + threadIdx.x;
    if (i < n4) {
        float4 v = ((const float4*)w)[i];
        union { __hip_bfloat16 h[4]; short4 s4; } u;
        u.h[0] = __float2bfloat16(v.x);
        u.h[1] = __float2bfloat16(v.y);
        u.h[2] = __float2bfloat16(v.z);
        u.h[3] = __float2bfloat16(v.w);
        *(short4*)(&wb[4 * i]) = u.s4;
    }
}

// ---------------------------------------------------------------- scan
// NUMERICS-CRITICAL: recurrence is marginally stable (measured ~3e5 worst-chain
// amplification of per-step rounding). Keep ops bit-identical to R1 version.
__global__ __launch_bounds__(64) void k_scan(const int* __restrict__ ids,
                                             const float* __restrict__ emb,
                                             const float* __restrict__ sT,
                                             const float* __restrict__ cT,
                                             float* __restrict__ states) {
    __shared__ float sL[LUT_N], cL[LUT_N];
    int d = threadIdx.x;
    int b = blockIdx.x;
    for (int i = d; i < LUT_N; i += 64) { sL[i] = sT[i]; cL[i] = cT[i]; }
    __syncthreads();
    float hr = 0.0f, hi = 0.0f;
    for (int t = 0; t < S_; ++t) {
        int   id = ids[b * S_ + t];
        float w  = emb[id * (2 * D_) + d];
        float bt = emb[id * (2 * D_) + D_ + d];
        float wl = 1.0f + fabsf(w);
        float tp = (float)t * PHI_F;
        float thr = hr / wl + bt + tp;
        float thi = hi / wl + bt + tp;
        float sr, cr, si, ci;
        lut_sc(sL, cL, thr, sr, cr);
        lut_sc(sL, cL, thi, si, ci);
        float nr = cr * ci - sr * si;
        float ni = cr * si + sr * ci;
        hr = nr; hi = ni;
        states[(b * S_ + t) * D_ + d] = nr + ni;
    }
}

// ---------------------------------------------------------------- q/k build
__global__ __launch_bounds__(256) void k_qk(const float* __restrict__ states,
                                            const float* __restrict__ wq,
                                            const float* __restrict__ bq,
                                            const float* __restrict__ wk,
                                            const float* __restrict__ bk,
                                            const float* __restrict__ sT,
                                            const float* __restrict__ cT,
                                            float* __restrict__ q,
                                            float* __restrict__ k) {
    __shared__ float sL[LUT_N], cL[LUT_N];
    for (int i = threadIdx.x; i < LUT_N; i += 256) { sL[i] = sT[i]; cL[i] = cT[i]; }
    __syncthreads();
    const int total = R_ * H_ * DH_;   // 262144
    for (int idx = blockIdx.x * 256 + threadIdx.x; idx < total; idx += gridDim.x * 256) {
        int j  = idx & (DH_ - 1);
        int h  = (idx >> 4) & (H_ - 1);
        int bt = idx >> 6;
        int t  = bt & (S_ - 1);
        float xp = states[idx];               // layout matches (bt*64 + h*16 + j)
        float tp = (float)t * PHI_F;
        int   hj = h * DH_ + j;
        float thq = xp / (1.0f + fabsf(wq[hj])) + bq[hj] + tp;
        float thk = xp / (1.0f + fabsf(wk[hj])) + bk[hj];
        float sq, cq, sk, ck;
        lut_sc(sL, cL, thq, sq, cq);
        lut_sc(sL, cL, thk, sk, ck);
        int base = bt * (H_ * 2 * DH_) + h * (2 * DH_) + j;
        q[base] = cq; q[base + DH_] = sq;
        k[base] = ck; k[base + DH_] = sk;
    }
}

// ---------------------------------------------------------------- attention
__global__ __launch_bounds__(256) void k_attn(const float* __restrict__ states,
                                              const float* __restrict__ q,
                                              const float* __restrict__ k,
                                              const float* __restrict__ wctx,
                                              float* __restrict__ x) {
    int bt = blockIdx.x;
    int b  = bt >> 9, t = bt & (S_ - 1);
    int tid = threadIdx.x;
    if (t == 0) {                       // has_ctx == 0 at t==0
        if (tid < D_) x[bt * D_ + tid] = states[bt * D_ + tid];
        return;
    }
    __shared__ float wlds[H_][S_];
    __shared__ float ql[H_][2 * DH_];
    __shared__ float cpart[4][D_];
    int h = tid >> 6, l = tid & 63;
    if (l < 2 * DH_) ql[h][l] = q[bt * 128 + h * 32 + l];
    __syncthreads();

    const float* kb = k + (size_t)(b * S_) * 128 + h * 32;
    float sc[8];
    float m = -INFINITY;
#pragma unroll
    for (int jj = 0; jj < 8; ++jj) {
        int s = l + jj * 64;
        float v = -INFINITY;
        if (s < t) {
            const float4* kp = (const float4*)(kb + (size_t)s * 128);
            float acc = 0.0f;
#pragma unroll
            for (int c = 0; c < 8; ++c) {
                float4 kv = kp[c];
                acc += kv.x * ql[h][c * 4 + 0] + kv.y * ql[h][c * 4 + 1]
                     + kv.z * ql[h][c * 4 + 2] + kv.w * ql[h][c * 4 + 3];
            }
            v = acc * 0.1767766952966369f;   // 1/sqrt(2*dh)
            m = fmaxf(m, v);
        }
        sc[jj] = v;
    }
    for (int o = 32; o; o >>= 1) m = fmaxf(m, __shfl_xor(m, o));
    float sum = 0.0f;
#pragma unroll
    for (int jj = 0; jj < 8; ++jj) {
        float e = expf(sc[jj] - m);      // expf(-inf)=0 handles the mask
        sc[jj] = e; sum += e;
    }
    for (int o = 32; o; o >>= 1) sum += __shfl_xor(sum, o);
    float inv = 1.0f / sum;
#pragma unroll
    for (int jj = 0; jj < 8; ++jj) {
        int s = l + jj * 64;
        if (s < S_) wlds[h][s] = sc[jj] * inv;
    }
    __syncthreads();
    {
        int d = tid & 63, p = tid >> 6;
        float acc = 0.0f;
        for (int s = p; s < t; s += 4) {
            float w4 = wlds[0][s] + wlds[1][s] + wlds[2][s] + wlds[3][s];
            acc += w4 * states[((size_t)b * S_ + s) * D_ + d];
        }
        cpart[p][d] = acc;
    }
    __syncthreads();
    if (tid < D_) {
        float c = cpart[0][tid] + cpart[1][tid] + cpart[2][tid] + cpart[3][tid];
        cpart[0][tid] = c;
    }
    __syncthreads();
    if (tid < D_) {
        float y = 0.0f;
        const float* wr = wctx + tid * D_;
        for (int d = 0; d < D_; ++d) y += cpart[0][d] * wr[d];
        x[bt * D_ + tid] = states[bt * D_ + tid] + y;
    }
}

// ---------------------------------------------------------------- residual phase block
__global__ __launch_bounds__(256) void k_resid(float* __restrict__ x,
                                               const float* __restrict__ Wres,
                                               const float* __restrict__ Bres,
                                               const float* __restrict__ wpr,
                                               const float* __restrict__ wpi,
                                               const float* __restrict__ sT,
                                               const float* __restrict__ cT,
                                               __hip_bfloat16* __restrict__ xb) {
    __shared__ float sL[LUT_N], cL[LUT_N];
    __shared__ float xv[D_];
    __shared__ float csum[N_], ssum[N_];
    int tid = threadIdx.x;
    for (int i = tid; i < LUT_N; i += 256) { sL[i] = sT[i]; cL[i] = cT[i]; }
    int n  = tid >> 1;
    int d0 = (tid & 1) * 32;
    for (int r = 0; r < 8; ++r) {
        int bt = blockIdx.x * 8 + r;
        int t  = bt & (S_ - 1);
        float tp = (float)t * PHI_F;
        __syncthreads();
        if (tid < D_) xv[tid] = x[bt * D_ + tid];
        __syncthreads();
        float cs = 0.0f, ss = 0.0f;
#pragma unroll
        for (int dd = 0; dd < 32; ++dd) {
            int d  = d0 + dd;
            int nd = n * D_ + d;
            float th = xv[d] / (1.0f + fabsf(Wres[nd])) + Bres[nd] + tp;
            float s, c;
            lut_sc(sL, cL, th, s, c);
            cs += c; ss += s;
        }
        cs += __shfl_xor(cs, 1);
        ss += __shfl_xor(ss, 1);
        if ((tid & 1) == 0) { csum[n] = cs; ssum[n] = ss; }
        __syncthreads();
        if (tid < D_) {
            float pre = 0.0f;
            const float* pr = wpr + tid * N_;
            const float* pi = wpi + tid * N_;
            for (int nn = 0; nn < N_; ++nn) pre += csum[nn] * pr[nn] + ssum[nn] * pi[nn];
            float sig = 1.0f / (1.0f + expf(-pre));
            float val = xv[tid] + pre * sig;
            x[bt * D_ + tid]  = val;
            xb[bt * D_ + tid] = __float2bfloat16(val);
        }
    }
}

// ---------------------------------------------------------------- output GEMM (bf16 MFMA)
// out[r,v] = sum_d x[r,d]*wout[v,d].  M=4096 N=32000 K=64.
// Block: 256 thr = 4 waves (2x2), tile 64M x 128N. 2 MFMAs per 16x16 frag (K=64).
// A frag (16x32): lane l holds A[l&15][(l>>4)*8 + j]      -> 16B load from xb row
// B frag (32x16): lane l holds B[(l>>4)*8 + j][l&15]      -> 16B load from wb row
// C frag: lane l reg i -> row (l>>4)*4+i, col l&15   [verified layout, m89]
__global__ __launch_bounds__(256) void k_out(const __hip_bfloat16* __restrict__ xb,
                                             const __hip_bfloat16* __restrict__ wb,
                                             float* __restrict__ out) {
    __shared__ float ot[64][132];   // pad 4 -> 16B-aligned rows, 2-way banks only
    int tid  = threadIdx.x;
    int wave = tid >> 6, l = tid & 63;
    int wr = wave >> 1, wc = wave & 1;
    int m0 = blockIdx.y * 64 + wr * 32;
    int c0 = blockIdx.x * 128 + wc * 64;
    int r  = l & 15;
    int ks = (l >> 4) * 8;

    short8_t a[2][2], b[4][2];
#pragma unroll
    for (int mi = 0; mi < 2; ++mi)
#pragma unroll
        for (int kk = 0; kk < 2; ++kk)
            a[mi][kk] = *reinterpret_cast<const short8_t*>(
                xb + (size_t)(m0 + mi * 16 + r) * 64 + kk * 32 + ks);
#pragma unroll
    for (int ni = 0; ni < 4; ++ni)
#pragma unroll
        for (int kk = 0; kk < 2; ++kk)
            b[ni][kk] = *reinterpret_cast<const short8_t*>(
                wb + (size_t)(c0 + ni * 16 + r) * 64 + kk * 32 + ks);

    f32x4 acc[2][4];
#pragma unroll
    for (int mi = 0; mi < 2; ++mi)
#pragma unroll
        for (int ni = 0; ni < 4; ++ni) {
            acc[mi][ni] = (f32x4){0.f, 0.f, 0.f, 0.f};
            acc[mi][ni] = __builtin_amdgcn_mfma_f32_16x16x32_bf16(
                a[mi][0], b[ni][0], acc[mi][ni], 0, 0, 0);
            acc[mi][ni] = __builtin_amdgcn_mfma_f32_16x16x32_bf16(
                a[mi][1], b[ni][1], acc[mi][ni], 0, 0, 0);
        }

    int kh = l >> 4;
#pragma unroll
    for (int mi = 0; mi < 2; ++mi)
#pragma unroll
        for (int ni = 0; ni < 4; ++ni)
#pragma unroll
            for (int i = 0; i < 4; ++i)
                ot[wr * 32 + mi * 16 + kh * 4 + i][wc * 64 + ni * 16 + r] = acc[mi][ni][i];
    __syncthreads();

    size_t rbase = blockIdx.y * 64;
    size_t cb    = blockIdx.x * 128;
#pragma unroll
    for (int j = 0; j < 8; ++j) {
        int idx = j * 256 + tid;          // 2048 float4s
        int row = idx >> 5, c4 = idx & 31;
        float4 v = *(const float4*)&ot[row][c4 * 4];
        *(float4*)&out[(rbase + row) * V_ + cb + c4 * 4] = v;
    }
}

// ---------------------------------------------------------------- launcher
extern "C" void kernel_launch(void* const* d_in, const int* in_sizes, int n_in,
                              void* d_out, int out_size, void* d_ws, size_t ws_size,
                              hipStream_t stream) {
    const int*   ids  = (const int*)  d_in[0];
    const float* emb  = (const float*)d_in[1];
    const float* wq   = (const float*)d_in[2];
    const float* bq   = (const float*)d_in[3];
    const float* wk   = (const float*)d_in[4];
    const float* bk   = (const float*)d_in[5];
    const float* wctx = (const float*)d_in[6];
    const float* Wres = (const float*)d_in[7];
    const float* Bres = (const float*)d_in[8];
    const float* wpr  = (const float*)d_in[9];
    const float* wpi  = (const float*)d_in[10];
    const float* wout = (const float*)d_in[11];
    float* out = (float*)d_out;

    float* sT     = (float*)d_ws;                 // 4096
    float* cT     = sT + LUT_N;                   // 4096
    float* states = cT + LUT_N;                   // 262144
    float* qbuf   = states + R_ * D_;             // 524288
    float* kbuf   = qbuf + R_ * H_ * 2 * DH_;     // 524288
    float* xbuf   = kbuf + R_ * H_ * 2 * DH_;     // 262144
    __hip_bfloat16* wb = (__hip_bfloat16*)(xbuf + R_ * D_);  // 2,048,000 bf16 (16B-aligned)
    __hip_bfloat16* xb = wb + (size_t)V_ * D_;               // 262,144 bf16

    k_tables<<<16, 256, 0, stream>>>(sT, cT);
    k_cvt   <<<(V_ * D_ / 4 + 255) / 256, 256, 0, stream>>>(wout, wb, V_ * D_ / 4);
    k_scan  <<<B_, 64, 0, stream>>>(ids, emb, sT, cT, states);
    k_qk    <<<64, 256, 0, stream>>>(states, wq, bq, wk, bk, sT, cT, qbuf, kbuf);
    k_attn  <<<R_, 256, 0, stream>>>(states, qbuf, kbuf, wctx, xbuf);
    k_resid <<<R_ / 8, 256, 0, stream>>>(xbuf, Wres, Bres, wpr, wpi, sT, cT, xb);
    k_out   <<<dim3(V_ / 128, R_ / 64), 256, 0, stream>>>(xb, wb, out);
}

// Round 3
// 426.217 us; speedup vs baseline: 1.8973x; 1.4922x over previous
//
#include <hip/hip_runtime.h>
#include <hip/hip_bf16.h>
#include <math.h>

#define PHI_F     1.618033988749895f
#define LUT_N     4096
#define LUT_INV   651.8986469044033f      /* 4096/(2*pi) rounded to f32 */
#define LUT_STEP  0.0015339807878856412f  /* 2*pi/4096  rounded to f32 */

#define B_  8
#define S_  512
#define D_  64
#define H_  4
#define DH_ 16
#define N_  128
#define V_  32000
#define R_  (B_ * S_)   /* 4096 rows */

typedef __attribute__((ext_vector_type(8))) short short8_t;
typedef __attribute__((ext_vector_type(4))) float f32x4;

// ---------------------------------------------------------------- LUT interp (scalar tables)
__device__ __forceinline__ void lut_sc(const float* __restrict__ sL,
                                       const float* __restrict__ cL,
                                       float th, float& s, float& c) {
    float pos = th * LUT_INV;
    float f0  = floorf(pos);
    float fr  = pos - f0;
    int   i0  = ((int)f0) & (LUT_N - 1);
    int   i1  = (i0 + 1) & (LUT_N - 1);
    float om  = 1.0f - fr;
    s = sL[i0] * om + sL[i1] * fr;
    c = cL[i0] * om + cL[i1] * fr;
}

// ---------------------------------------------------------------- LUT interp (float2 {sin,cos})
__device__ __forceinline__ void lut2(const float2* __restrict__ sc,
                                     float th, float& s, float& c) {
    float pos = th * LUT_INV;
    float f0  = floorf(pos);
    float fr  = pos - f0;
    int   i0  = ((int)f0) & (LUT_N - 1);
    int   i1  = (i0 + 1) & (LUT_N - 1);
    float2 p0 = sc[i0];
    float2 p1 = sc[i1];
    float om  = 1.0f - fr;
    s = p0.x * om + p1.x * fr;
    c = p0.y * om + p1.y * fr;
}

// ---------------------------------------------------------------- table build
__global__ void k_tables(float* __restrict__ sT, float* __restrict__ cT,
                         float2* __restrict__ scT) {
    int i = blockIdx.x * blockDim.x + threadIdx.x;
    if (i < LUT_N) {
        float g = (float)i * LUT_STEP;        // matches np.arange(f32) * (2pi/4096)
        float s = (float)sin((double)g);
        float c = (float)cos((double)g);
        sT[i] = s; cT[i] = c;
        scT[i] = make_float2(s, c);
    }
}

// ---------------------------------------------------------------- wout -> bf16
__global__ __launch_bounds__(256) void k_cvt(const float* __restrict__ w,
                                             __hip_bfloat16* __restrict__ wb,
                                             int n4) {
    int i = blockIdx.x * 256 + threadIdx.x;
    if (i < n4) {
        float4 v = ((const float4*)w)[i];
        union { __hip_bfloat16 h[4]; short4 s4; } u;
        u.h[0] = __float2bfloat16(v.x);
        u.h[1] = __float2bfloat16(v.y);
        u.h[2] = __float2bfloat16(v.z);
        u.h[3] = __float2bfloat16(v.w);
        *(short4*)(&wb[4 * i]) = u.s4;
    }
}

// ---------------------------------------------------------------- embedding pre-gather
// wlbt[bt*64+d] = {1+|w_emb|, b_emb} — removes the data-dependent 2-level gather
// from the scan's serial chain. wl computed identically to reference.
__global__ __launch_bounds__(256) void k_pre(const int* __restrict__ ids,
                                             const float* __restrict__ emb,
                                             float2* __restrict__ wlbt) {
    int idx = blockIdx.x * 256 + threadIdx.x;   // over R_*D_ = 262144
    int d  = idx & (D_ - 1);
    int bt = idx >> 6;
    int id = ids[bt];
    float w = emb[(size_t)id * (2 * D_) + d];
    float b = emb[(size_t)id * (2 * D_) + D_ + d];
    wlbt[idx] = make_float2(1.0f + fabsf(w), b);
}

// ---------------------------------------------------------------- scan
// NUMERICS-CRITICAL: recurrence is marginally stable; keep carried-chain ops
// bit-identical to reference (exact div, same add order, same interp order).
// 8 blocks x 64 threads; 8-step software pipeline hides global load latency.
__global__ __launch_bounds__(64) void k_scan(const float2* __restrict__ wlbt,
                                             const float2* __restrict__ scT,
                                             float* __restrict__ states) {
    __shared__ float2 sc[LUT_N];
    int d = threadIdx.x;
    int b = blockIdx.x;
    for (int i = d; i < LUT_N; i += 64) sc[i] = scT[i];
    __syncthreads();

    const float2* src  = wlbt + (size_t)b * S_ * D_ + d;
    float*        outp = states + (size_t)b * S_ * D_ + d;

    float2 cur[8], nxt[8];
#pragma unroll
    for (int j = 0; j < 8; ++j) cur[j] = src[j * D_];

    float hr = 0.0f, hi = 0.0f;
    for (int tc = 0; tc < S_; tc += 8) {
        int tn = (tc + 8) & (S_ - 1);        // last chunk wraps; prefetch unused
#pragma unroll
        for (int j = 0; j < 8; ++j) nxt[j] = src[(tn + j) * D_];
#pragma unroll
        for (int j = 0; j < 8; ++j) {
            int   t   = tc + j;
            float wl  = cur[j].x;
            float btv = cur[j].y;
            float tp  = (float)t * PHI_F;
            float thr = hr / wl + btv + tp;
            float thi = hi / wl + btv + tp;
            float sr, cr, si, ci;
            lut2(sc, thr, sr, cr);
            lut2(sc, thi, si, ci);
            float nr = cr * ci - sr * si;
            float ni = cr * si + sr * ci;
            hr = nr; hi = ni;
            outp[t * D_] = nr + ni;
        }
#pragma unroll
        for (int j = 0; j < 8; ++j) cur[j] = nxt[j];
    }
}

// ---------------------------------------------------------------- q/k build
__global__ __launch_bounds__(256) void k_qk(const float* __restrict__ states,
                                            const float* __restrict__ wq,
                                            const float* __restrict__ bq,
                                            const float* __restrict__ wk,
                                            const float* __restrict__ bk,
                                            const float* __restrict__ sT,
                                            const float* __restrict__ cT,
                                            float* __restrict__ q,
                                            float* __restrict__ k) {
    __shared__ float sL[LUT_N], cL[LUT_N];
    for (int i = threadIdx.x; i < LUT_N; i += 256) { sL[i] = sT[i]; cL[i] = cT[i]; }
    __syncthreads();
    const int total = R_ * H_ * DH_;   // 262144
    for (int idx = blockIdx.x * 256 + threadIdx.x; idx < total; idx += gridDim.x * 256) {
        int j  = idx & (DH_ - 1);
        int h  = (idx >> 4) & (H_ - 1);
        int bt = idx >> 6;
        int t  = bt & (S_ - 1);
        float xp = states[idx];               // layout matches (bt*64 + h*16 + j)
        float tp = (float)t * PHI_F;
        int   hj = h * DH_ + j;
        float thq = xp / (1.0f + fabsf(wq[hj])) + bq[hj] + tp;
        float thk = xp / (1.0f + fabsf(wk[hj])) + bk[hj];
        float sq, cq, sk, ck;
        lut_sc(sL, cL, thq, sq, cq);
        lut_sc(sL, cL, thk, sk, ck);
        int base = bt * (H_ * 2 * DH_) + h * (2 * DH_) + j;
        q[base] = cq; q[base + DH_] = sq;
        k[base] = ck; k[base + DH_] = sk;
    }
}

// ---------------------------------------------------------------- attention
__global__ __launch_bounds__(256) void k_attn(const float* __restrict__ states,
                                              const float* __restrict__ q,
                                              const float* __restrict__ k,
                                              const float* __restrict__ wctx,
                                              float* __restrict__ x) {
    int bt = blockIdx.x;
    int b  = bt >> 9, t = bt & (S_ - 1);
    int tid = threadIdx.x;
    if (t == 0) {                       // has_ctx == 0 at t==0
        if (tid < D_) x[bt * D_ + tid] = states[bt * D_ + tid];
        return;
    }
    __shared__ float wlds[H_][S_];
    __shared__ float ql[H_][2 * DH_];
    __shared__ float cpart[4][D_];
    int h = tid >> 6, l = tid & 63;
    if (l < 2 * DH_) ql[h][l] = q[bt * 128 + h * 32 + l];
    __syncthreads();

    const float* kb = k + (size_t)(b * S_) * 128 + h * 32;
    float sc[8];
    float m = -INFINITY;
#pragma unroll
    for (int jj = 0; jj < 8; ++jj) {
        int s = l + jj * 64;
        float v = -INFINITY;
        if (s < t) {
            const float4* kp = (const float4*)(kb + (size_t)s * 128);
            float acc = 0.0f;
#pragma unroll
            for (int c = 0; c < 8; ++c) {
                float4 kv = kp[c];
                acc += kv.x * ql[h][c * 4 + 0] + kv.y * ql[h][c * 4 + 1]
                     + kv.z * ql[h][c * 4 + 2] + kv.w * ql[h][c * 4 + 3];
            }
            v = acc * 0.1767766952966369f;   // 1/sqrt(2*dh)
            m = fmaxf(m, v);
        }
        sc[jj] = v;
    }
    for (int o = 32; o; o >>= 1) m = fmaxf(m, __shfl_xor(m, o));
    float sum = 0.0f;
#pragma unroll
    for (int jj = 0; jj < 8; ++jj) {
        float e = expf(sc[jj] - m);      // expf(-inf)=0 handles the mask
        sc[jj] = e; sum += e;
    }
    for (int o = 32; o; o >>= 1) sum += __shfl_xor(sum, o);
    float inv = 1.0f / sum;
#pragma unroll
    for (int jj = 0; jj < 8; ++jj) {
        int s = l + jj * 64;
        if (s < S_) wlds[h][s] = sc[jj] * inv;
    }
    __syncthreads();
    {
        int d = tid & 63, p = tid >> 6;
        float acc = 0.0f;
        for (int s = p; s < t; s += 4) {
            float w4 = wlds[0][s] + wlds[1][s] + wlds[2][s] + wlds[3][s];
            acc += w4 * states[((size_t)b * S_ + s) * D_ + d];
        }
        cpart[p][d] = acc;
    }
    __syncthreads();
    if (tid < D_) {
        float c = cpart[0][tid] + cpart[1][tid] + cpart[2][tid] + cpart[3][tid];
        cpart[0][tid] = c;
    }
    __syncthreads();
    if (tid < D_) {
        float y = 0.0f;
        const float* wr = wctx + tid * D_;
        for (int d = 0; d < D_; ++d) y += cpart[0][d] * wr[d];
        x[bt * D_ + tid] = states[bt * D_ + tid] + y;
    }
}

// ---------------------------------------------------------------- residual phase block
__global__ __launch_bounds__(256) void k_resid(float* __restrict__ x,
                                               const float* __restrict__ Wres,
                                               const float* __restrict__ Bres,
                                               const float* __restrict__ wpr,
                                               const float* __restrict__ wpi,
                                               const float* __restrict__ sT,
                                               const float* __restrict__ cT,
                                               __hip_bfloat16* __restrict__ xb) {
    __shared__ float sL[LUT_N], cL[LUT_N];
    __shared__ float xv[D_];
    __shared__ float csum[N_], ssum[N_];
    int tid = threadIdx.x;
    for (int i = tid; i < LUT_N; i += 256) { sL[i] = sT[i]; cL[i] = cT[i]; }
    int n  = tid >> 1;
    int d0 = (tid & 1) * 32;
    for (int r = 0; r < 8; ++r) {
        int bt = blockIdx.x * 8 + r;
        int t  = bt & (S_ - 1);
        float tp = (float)t * PHI_F;
        __syncthreads();
        if (tid < D_) xv[tid] = x[bt * D_ + tid];
        __syncthreads();
        float cs = 0.0f, ss = 0.0f;
#pragma unroll
        for (int dd = 0; dd < 32; ++dd) {
            int d  = d0 + dd;
            int nd = n * D_ + d;
            float th = xv[d] / (1.0f + fabsf(Wres[nd])) + Bres[nd] + tp;
            float s, c;
            lut_sc(sL, cL, th, s, c);
            cs += c; ss += s;
        }
        cs += __shfl_xor(cs, 1);
        ss += __shfl_xor(ss, 1);
        if ((tid & 1) == 0) { csum[n] = cs; ssum[n] = ss; }
        __syncthreads();
        if (tid < D_) {
            float pre = 0.0f;
            const float* pr = wpr + tid * N_;
            const float* pi = wpi + tid * N_;
            for (int nn = 0; nn < N_; ++nn) pre += csum[nn] * pr[nn] + ssum[nn] * pi[nn];
            float sig = 1.0f / (1.0f + expf(-pre));
            float val = xv[tid] + pre * sig;
            x[bt * D_ + tid]  = val;
            xb[bt * D_ + tid] = __float2bfloat16(val);
        }
    }
}

// ---------------------------------------------------------------- output GEMM (bf16 MFMA)
// out[r,v] = sum_d x[r,d]*wout[v,d].  M=4096 N=32000 K=64.
// Block: 256 thr = 4 waves (2x2), tile 64M x 128N. 2 MFMAs per 16x16 frag (K=64).
__global__ __launch_bounds__(256) void k_out(const __hip_bfloat16* __restrict__ xb,
                                             const __hip_bfloat16* __restrict__ wb,
                                             float* __restrict__ out) {
    __shared__ float ot[64][132];   // pad 4 -> 16B-aligned rows, 2-way banks only
    int tid  = threadIdx.x;
    int wave = tid >> 6, l = tid & 63;
    int wr = wave >> 1, wc = wave & 1;
    int m0 = blockIdx.y * 64 + wr * 32;
    int c0 = blockIdx.x * 128 + wc * 64;
    int r  = l & 15;
    int ks = (l >> 4) * 8;

    short8_t a[2][2], b[4][2];
#pragma unroll
    for (int mi = 0; mi < 2; ++mi)
#pragma unroll
        for (int kk = 0; kk < 2; ++kk)
            a[mi][kk] = *reinterpret_cast<const short8_t*>(
                xb + (size_t)(m0 + mi * 16 + r) * 64 + kk * 32 + ks);
#pragma unroll
    for (int ni = 0; ni < 4; ++ni)
#pragma unroll
        for (int kk = 0; kk < 2; ++kk)
            b[ni][kk] = *reinterpret_cast<const short8_t*>(
                wb + (size_t)(c0 + ni * 16 + r) * 64 + kk * 32 + ks);

    f32x4 acc[2][4];
#pragma unroll
    for (int mi = 0; mi < 2; ++mi)
#pragma unroll
        for (int ni = 0; ni < 4; ++ni) {
            acc[mi][ni] = (f32x4){0.f, 0.f, 0.f, 0.f};
            acc[mi][ni] = __builtin_amdgcn_mfma_f32_16x16x32_bf16(
                a[mi][0], b[ni][0], acc[mi][ni], 0, 0, 0);
            acc[mi][ni] = __builtin_amdgcn_mfma_f32_16x16x32_bf16(
                a[mi][1], b[ni][1], acc[mi][ni], 0, 0, 0);
        }

    int kh = l >> 4;
#pragma unroll
    for (int mi = 0; mi < 2; ++mi)
#pragma unroll
        for (int ni = 0; ni < 4; ++ni)
#pragma unroll
            for (int i = 0; i < 4; ++i)
                ot[wr * 32 + mi * 16 + kh * 4 + i][wc * 64 + ni * 16 + r] = acc[mi][ni][i];
    __syncthreads();

    size_t rbase = blockIdx.y * 64;
    size_t cb    = blockIdx.x * 128;
#pragma unroll
    for (int j = 0; j < 8; ++j) {
        int idx = j * 256 + tid;          // 2048 float4s
        int row = idx >> 5, c4 = idx & 31;
        float4 v = *(const float4*)&ot[row][c4 * 4];
        *(float4*)&out[(rbase + row) * V_ + cb + c4 * 4] = v;
    }
}

// ---------------------------------------------------------------- launcher
extern "C" void kernel_launch(void* const* d_in, const int* in_sizes, int n_in,
                              void* d_out, int out_size, void* d_ws, size_t ws_size,
                              hipStream_t stream) {
    const int*   ids  = (const int*)  d_in[0];
    const float* emb  = (const float*)d_in[1];
    const float* wq   = (const float*)d_in[2];
    const float* bq   = (const float*)d_in[3];
    const float* wk   = (const float*)d_in[4];
    const float* bk   = (const float*)d_in[5];
    const float* wctx = (const float*)d_in[6];
    const float* Wres = (const float*)d_in[7];
    const float* Bres = (const float*)d_in[8];
    const float* wpr  = (const float*)d_in[9];
    const float* wpi  = (const float*)d_in[10];
    const float* wout = (const float*)d_in[11];
    float* out = (float*)d_out;

    float* sT     = (float*)d_ws;                 // 4096
    float* cT     = sT + LUT_N;                   // 4096
    float* states = cT + LUT_N;                   // 262144
    float* qbuf   = states + R_ * D_;             // 524288
    float* kbuf   = qbuf + R_ * H_ * 2 * DH_;     // 524288
    float* xbuf   = kbuf + R_ * H_ * 2 * DH_;     // 262144
    __hip_bfloat16* wb = (__hip_bfloat16*)(xbuf + R_ * D_);  // 2,048,000 bf16
    __hip_bfloat16* xb = wb + (size_t)V_ * D_;               // 262,144 bf16
    float2* scT  = (float2*)(xb + R_ * D_);       // 4096 float2 (8B-aligned)
    float2* wlbt = scT + LUT_N;                   // 262,144 float2

    k_tables<<<16, 256, 0, stream>>>(sT, cT, scT);
    k_cvt   <<<(V_ * D_ / 4 + 255) / 256, 256, 0, stream>>>(wout, wb, V_ * D_ / 4);
    k_pre   <<<R_ * D_ / 256, 256, 0, stream>>>(ids, emb, wlbt);
    k_scan  <<<B_, 64, 0, stream>>>(wlbt, scT, states);
    k_qk    <<<64, 256, 0, stream>>>(states, wq, bq, wk, bk, sT, cT, qbuf, kbuf);
    k_attn  <<<R_, 256, 0, stream>>>(states, qbuf, kbuf, wctx, xbuf);
    k_resid <<<R_ / 8, 256, 0, stream>>>(xbuf, Wres, Bres, wpr, wpi, sT, cT, xb);
    k_out   <<<dim3(V_ / 128, R_ / 64), 256, 0, stream>>>(xb, wb, out);
}

// Round 4
// 359.930 us; speedup vs baseline: 2.2467x; 1.1842x over previous
//
#include <hip/hip_runtime.h>
#include <hip/hip_bf16.h>
#include <math.h>

#define PHI_F     1.618033988749895f
#define LUT_N     4096
#define LUT_INV   651.8986469044033f      /* 4096/(2*pi) rounded to f32 */
#define LUT_STEP  0.0015339807878856412f  /* 2*pi/4096  rounded to f32 */

#define B_  8
#define S_  512
#define D_  64
#define H_  4
#define DH_ 16
#define N_  128
#define V_  32000
#define R_  (B_ * S_)   /* 4096 rows */

typedef __attribute__((ext_vector_type(8))) short short8_t;
typedef __attribute__((ext_vector_type(4))) float f32x4;

// ---------------------------------------------------------------- LUT interp (float2 {sin,cos})
__device__ __forceinline__ void lut2(const float2* __restrict__ sc,
                                     float th, float& s, float& c) {
    float pos = th * LUT_INV;
    float f0  = floorf(pos);
    float fr  = pos - f0;
    int   i0  = ((int)f0) & (LUT_N - 1);
    int   i1  = (i0 + 1) & (LUT_N - 1);
    float2 p0 = sc[i0];
    float2 p1 = sc[i1];
    float om  = 1.0f - fr;
    s = p0.x * om + p1.x * fr;
    c = p0.y * om + p1.y * fr;
}

// ---------------------------------------------------------------- table build
__global__ void k_tables(float2* __restrict__ scT) {
    int i = blockIdx.x * blockDim.x + threadIdx.x;
    if (i < LUT_N) {
        float g = (float)i * LUT_STEP;        // matches np.arange(f32) * (2pi/4096)
        scT[i] = make_float2((float)sin((double)g), (float)cos((double)g));
    }
}

// ---------------------------------------------------------------- wout -> bf16
__global__ __launch_bounds__(256) void k_cvt(const float* __restrict__ w,
                                             __hip_bfloat16* __restrict__ wb,
                                             int n4) {
    int i = blockIdx.x * 256 + threadIdx.x;
    if (i < n4) {
        float4 v = ((const float4*)w)[i];
        union { __hip_bfloat16 h[4]; short4 s4; } u;
        u.h[0] = __float2bfloat16(v.x);
        u.h[1] = __float2bfloat16(v.y);
        u.h[2] = __float2bfloat16(v.z);
        u.h[3] = __float2bfloat16(v.w);
        *(short4*)(&wb[4 * i]) = u.s4;
    }
}

// ---------------------------------------------------------------- resid weight prep
// ibres[nd] = {1/(1+|Wres|), Bres}; wpT[nn*64+d] = {wpr[d,nn], wpi[d,nn]}
__global__ __launch_bounds__(256) void k_wpre(const float* __restrict__ Wres,
                                              const float* __restrict__ Bres,
                                              const float* __restrict__ wpr,
                                              const float* __restrict__ wpi,
                                              float2* __restrict__ ibres,
                                              float2* __restrict__ wpT) {
    int idx = blockIdx.x * 256 + threadIdx.x;
    if (idx < N_ * D_) {
        ibres[idx] = make_float2(1.0f / (1.0f + fabsf(Wres[idx])), Bres[idx]);
        int nn = idx >> 6, d = idx & 63;
        wpT[idx] = make_float2(wpr[d * N_ + nn], wpi[d * N_ + nn]);
    }
}

// ---------------------------------------------------------------- embedding pre-gather
__global__ __launch_bounds__(256) void k_pre(const int* __restrict__ ids,
                                             const float* __restrict__ emb,
                                             float2* __restrict__ wlbt) {
    int idx = blockIdx.x * 256 + threadIdx.x;   // over R_*D_ = 262144
    int d  = idx & (D_ - 1);
    int bt = idx >> 6;
    int id = ids[bt];
    float w = emb[(size_t)id * (2 * D_) + d];
    float b = emb[(size_t)id * (2 * D_) + D_ + d];
    wlbt[idx] = make_float2(1.0f + fabsf(w), b);
}

// ---------------------------------------------------------------- scan
// NUMERICS-CRITICAL: marginally-stable recurrence; ops bit-identical to ref
// (exact div, same add/interp order). 8-step pipeline hides global latency.
__global__ __launch_bounds__(64) void k_scan(const float2* __restrict__ wlbt,
                                             const float2* __restrict__ scT,
                                             float* __restrict__ states) {
    __shared__ float2 sc[LUT_N];
    int d = threadIdx.x;
    int b = blockIdx.x;
    for (int i = d; i < LUT_N; i += 64) sc[i] = scT[i];
    __syncthreads();

    const float2* src  = wlbt + (size_t)b * S_ * D_ + d;
    float*        outp = states + (size_t)b * S_ * D_ + d;

    float2 cur[8], nxt[8];
#pragma unroll
    for (int j = 0; j < 8; ++j) cur[j] = src[j * D_];

    float hr = 0.0f, hi = 0.0f;
    for (int tc = 0; tc < S_; tc += 8) {
        int tn = (tc + 8) & (S_ - 1);
#pragma unroll
        for (int j = 0; j < 8; ++j) nxt[j] = src[(tn + j) * D_];
#pragma unroll
        for (int j = 0; j < 8; ++j) {
            int   t   = tc + j;
            float wl  = cur[j].x;
            float btv = cur[j].y;
            float tp  = (float)t * PHI_F;
            float thr = hr / wl + btv + tp;
            float thi = hi / wl + btv + tp;
            float sr, cr, si, ci;
            lut2(sc, thr, sr, cr);
            lut2(sc, thi, si, ci);
            float nr = cr * ci - sr * si;
            float ni = cr * si + sr * ci;
            hr = nr; hi = ni;
            outp[t * D_] = nr + ni;
        }
#pragma unroll
        for (int j = 0; j < 8; ++j) cur[j] = nxt[j];
    }
}

// ---------------------------------------------------------------- q/k build (k transposed)
__global__ __launch_bounds__(256) void k_qk(const float* __restrict__ states,
                                            const float* __restrict__ wq,
                                            const float* __restrict__ bq,
                                            const float* __restrict__ wk,
                                            const float* __restrict__ bk,
                                            const float2* __restrict__ scT,
                                            float* __restrict__ q,
                                            float* __restrict__ kT) {
    __shared__ float2 sc[LUT_N];
    for (int i = threadIdx.x; i < LUT_N; i += 256) sc[i] = scT[i];
    __syncthreads();
    const int total = R_ * H_ * DH_;   // 262144
    for (int idx = blockIdx.x * 256 + threadIdx.x; idx < total; idx += gridDim.x * 256) {
        int j  = idx & (DH_ - 1);
        int h  = (idx >> 4) & (H_ - 1);
        int bt = idx >> 6;
        int t  = bt & (S_ - 1);
        int b  = bt >> 9;
        float xp = states[idx];
        float tp = (float)t * PHI_F;
        int   hj = h * DH_ + j;
        float thq = xp / (1.0f + fabsf(wq[hj])) + bq[hj] + tp;
        float thk = xp / (1.0f + fabsf(wk[hj])) + bk[hj];
        float sq, cq, sk, ck;
        lut2(sc, thq, sq, cq);
        lut2(sc, thk, sk, ck);
        int base = bt * (H_ * 2 * DH_) + h * (2 * DH_) + j;
        q[base] = cq; q[base + DH_] = sq;
        size_t kb = ((size_t)(b * H_ + h) * 32 + j) * S_ + t;
        kT[kb] = ck; kT[kb + 16 * S_] = sk;
    }
}

// ---------------------------------------------------------------- attention
__global__ __launch_bounds__(256) void k_attn(const float* __restrict__ states,
                                              const float* __restrict__ q,
                                              const float* __restrict__ kT,
                                              const float* __restrict__ wctx,
                                              float* __restrict__ x) {
    int bt = blockIdx.x;
    int b  = bt >> 9, t = bt & (S_ - 1);
    int tid = threadIdx.x;
    if (t == 0) {                       // has_ctx == 0 at t==0
        if (tid < D_) x[bt * D_ + tid] = states[bt * D_ + tid];
        return;
    }
    __shared__ float wlds[H_][S_];
    __shared__ float ql[H_][2 * DH_];
    __shared__ float cpart[4][D_];
    int h = tid >> 6, l = tid & 63;
    if (l < 2 * DH_) ql[h][l] = q[bt * 128 + h * 32 + l];
    __syncthreads();

    const float* kTb = kT + (size_t)(b * H_ + h) * 32 * S_;
    float sc[8];
    float m = -INFINITY;
#pragma unroll
    for (int jj = 0; jj < 8; ++jj) {
        int s = l + jj * 64;
        float v = -INFINITY;
        if (s < t) {
            float acc = 0.0f;
#pragma unroll
            for (int c = 0; c < 32; ++c)
                acc = fmaf(kTb[c * S_ + s], ql[h][c], acc);   // lane-contiguous loads
            v = acc * 0.1767766952966369f;   // 1/sqrt(2*dh)
            m = fmaxf(m, v);
        }
        sc[jj] = v;
    }
    for (int o = 32; o; o >>= 1) m = fmaxf(m, __shfl_xor(m, o));
    float sum = 0.0f;
#pragma unroll
    for (int jj = 0; jj < 8; ++jj) {
        float e = __expf(sc[jj] - m);    // __expf(-inf)=0 handles the mask
        sc[jj] = e; sum += e;
    }
    for (int o = 32; o; o >>= 1) sum += __shfl_xor(sum, o);
    float inv = 1.0f / sum;
#pragma unroll
    for (int jj = 0; jj < 8; ++jj) {
        int s = l + jj * 64;
        if (s < S_) wlds[h][s] = sc[jj] * inv;
    }
    __syncthreads();
    {
        int d = tid & 63, p = tid >> 6;
        float acc = 0.0f;
        for (int s = p; s < t; s += 4) {
            float w4 = wlds[0][s] + wlds[1][s] + wlds[2][s] + wlds[3][s];
            acc += w4 * states[((size_t)b * S_ + s) * D_ + d];
        }
        cpart[p][d] = acc;
    }
    __syncthreads();
    if (tid < D_) {
        float c = cpart[0][tid] + cpart[1][tid] + cpart[2][tid] + cpart[3][tid];
        cpart[0][tid] = c;
    }
    __syncthreads();
    if (tid < D_) {
        float y = 0.0f;
        const float* wr = wctx + tid * D_;
        for (int d = 0; d < D_; ++d) y += cpart[0][d] * wr[d];
        x[bt * D_ + tid] = states[bt * D_ + tid] + y;
    }
}

// ---------------------------------------------------------------- residual phase block
// 512 blocks x 256 thr, 8 rows each. Eval: thread=(n, half-of-d), reg-hoisted
// {inv,B}; projection: 4-way split over all threads with transposed wpT.
__global__ __launch_bounds__(256) void k_resid(const float* __restrict__ x,
                                               const float2* __restrict__ ibres,
                                               const float2* __restrict__ wpT,
                                               const float2* __restrict__ scT,
                                               __hip_bfloat16* __restrict__ xb) {
    __shared__ float2 sc[LUT_N];
    __shared__ float xv[D_];
    __shared__ float csum[N_], ssum[N_];
    __shared__ float part[4][D_];
    int tid = threadIdx.x;
    for (int i = tid; i < LUT_N; i += 256) sc[i] = scT[i];
    int n  = tid >> 1;
    int d0 = (tid & 1) * 32;
    float2 ib[32];
#pragma unroll
    for (int dd = 0; dd < 32; ++dd) ib[dd] = ibres[n * D_ + d0 + dd];
    int g = tid >> 6, dl = tid & 63;
    for (int r = 0; r < 8; ++r) {
        int bt = blockIdx.x * 8 + r;
        int t  = bt & (S_ - 1);
        float tp = (float)t * PHI_F;
        __syncthreads();
        if (tid < D_) xv[tid] = x[bt * D_ + tid];
        __syncthreads();
        float cs = 0.0f, ss = 0.0f;
#pragma unroll
        for (int dd = 0; dd < 32; ++dd) {
            float th = fmaf(xv[d0 + dd], ib[dd].x, ib[dd].y) + tp;
            float s, c;
            lut2(sc, th, s, c);
            cs += c; ss += s;
        }
        cs += __shfl_xor(cs, 1);
        ss += __shfl_xor(ss, 1);
        if ((tid & 1) == 0) { csum[n] = cs; ssum[n] = ss; }
        __syncthreads();
        float acc = 0.0f;
#pragma unroll
        for (int nn = 0; nn < 32; ++nn) {
            float2 w = wpT[(g * 32 + nn) * D_ + dl];
            acc = fmaf(csum[g * 32 + nn], w.x, fmaf(ssum[g * 32 + nn], w.y, acc));
        }
        part[g][dl] = acc;
        __syncthreads();
        if (tid < D_) {
            float pre = part[0][tid] + part[1][tid] + part[2][tid] + part[3][tid];
            float sig = 1.0f / (1.0f + __expf(-pre));
            xb[bt * D_ + tid] = __float2bfloat16(xv[tid] + pre * sig);
        }
    }
}

// ---------------------------------------------------------------- output GEMM (bf16 MFMA)
// out[r,v] = sum_d x[r,d]*wout[v,d]. M=4096 N=32000 K=64. Tile 64M x 256N
// (2 x 128-col chunks reusing A frags). 4 waves (2x2).
__global__ __launch_bounds__(256) void k_out(const __hip_bfloat16* __restrict__ xb,
                                             const __hip_bfloat16* __restrict__ wb,
                                             float* __restrict__ out) {
    __shared__ float ot[64][132];
    int tid  = threadIdx.x;
    int wave = tid >> 6, l = tid & 63;
    int wr = wave >> 1, wc = wave & 1;
    int m0 = blockIdx.y * 64 + wr * 32;
    int r  = l & 15;
    int ks = (l >> 4) * 8;
    int kh = l >> 4;

    short8_t a[2][2];
#pragma unroll
    for (int mi = 0; mi < 2; ++mi)
#pragma unroll
        for (int kk = 0; kk < 2; ++kk)
            a[mi][kk] = *reinterpret_cast<const short8_t*>(
                xb + (size_t)(m0 + mi * 16 + r) * 64 + kk * 32 + ks);

    for (int ch = 0; ch < 2; ++ch) {
        int c0 = blockIdx.x * 256 + ch * 128 + wc * 64;
        short8_t b[4][2];
#pragma unroll
        for (int ni = 0; ni < 4; ++ni)
#pragma unroll
            for (int kk = 0; kk < 2; ++kk)
                b[ni][kk] = *reinterpret_cast<const short8_t*>(
                    wb + (size_t)(c0 + ni * 16 + r) * 64 + kk * 32 + ks);

        f32x4 acc[2][4];
#pragma unroll
        for (int mi = 0; mi < 2; ++mi)
#pragma unroll
            for (int ni = 0; ni < 4; ++ni) {
                acc[mi][ni] = (f32x4){0.f, 0.f, 0.f, 0.f};
                acc[mi][ni] = __builtin_amdgcn_mfma_f32_16x16x32_bf16(
                    a[mi][0], b[ni][0], acc[mi][ni], 0, 0, 0);
                acc[mi][ni] = __builtin_amdgcn_mfma_f32_16x16x32_bf16(
                    a[mi][1], b[ni][1], acc[mi][ni], 0, 0, 0);
            }

        if (ch) __syncthreads();          // ot reuse hazard
#pragma unroll
        for (int mi = 0; mi < 2; ++mi)
#pragma unroll
            for (int ni = 0; ni < 4; ++ni)
#pragma unroll
                for (int i = 0; i < 4; ++i)
                    ot[wr * 32 + mi * 16 + kh * 4 + i][wc * 64 + ni * 16 + r] = acc[mi][ni][i];
        __syncthreads();

        size_t rbase = blockIdx.y * 64;
        size_t cb    = (size_t)blockIdx.x * 256 + ch * 128;
#pragma unroll
        for (int j = 0; j < 8; ++j) {
            int idx = j * 256 + tid;      // 2048 float4s
            int row = idx >> 5, c4 = idx & 31;
            float4 v = *(const float4*)&ot[row][c4 * 4];
            *(float4*)&out[(rbase + row) * V_ + cb + c4 * 4] = v;
        }
    }
}

// ---------------------------------------------------------------- launcher
extern "C" void kernel_launch(void* const* d_in, const int* in_sizes, int n_in,
                              void* d_out, int out_size, void* d_ws, size_t ws_size,
                              hipStream_t stream) {
    const int*   ids  = (const int*)  d_in[0];
    const float* emb  = (const float*)d_in[1];
    const float* wq   = (const float*)d_in[2];
    const float* bq   = (const float*)d_in[3];
    const float* wk   = (const float*)d_in[4];
    const float* bk   = (const float*)d_in[5];
    const float* wctx = (const float*)d_in[6];
    const float* Wres = (const float*)d_in[7];
    const float* Bres = (const float*)d_in[8];
    const float* wpr  = (const float*)d_in[9];
    const float* wpi  = (const float*)d_in[10];
    const float* wout = (const float*)d_in[11];
    float* out = (float*)d_out;

    float* states = (float*)d_ws;                 // 262144
    float* qbuf   = states + R_ * D_;             // 524288
    float* kTbuf  = qbuf + R_ * 128;              // 524288 (b,h,32,S)
    float* xbuf   = kTbuf + B_ * H_ * 32 * S_;    // 262144
    __hip_bfloat16* wb = (__hip_bfloat16*)(xbuf + R_ * D_);  // 2,048,000 bf16
    __hip_bfloat16* xb = wb + (size_t)V_ * D_;               // 262,144 bf16
    float2* scT   = (float2*)(xb + R_ * D_);      // 4096 float2
    float2* wlbt  = scT + LUT_N;                  // 262,144 float2
    float2* ibres = wlbt + R_ * D_;               // 8192 float2
    float2* wpT   = ibres + N_ * D_;              // 8192 float2

    k_tables<<<16, 256, 0, stream>>>(scT);
    k_cvt   <<<(V_ * D_ / 4 + 255) / 256, 256, 0, stream>>>(wout, wb, V_ * D_ / 4);
    k_wpre  <<<(N_ * D_ + 255) / 256, 256, 0, stream>>>(Wres, Bres, wpr, wpi, ibres, wpT);
    k_pre   <<<R_ * D_ / 256, 256, 0, stream>>>(ids, emb, wlbt);
    k_scan  <<<B_, 64, 0, stream>>>(wlbt, scT, states);
    k_qk    <<<64, 256, 0, stream>>>(states, wq, bq, wk, bk, scT, qbuf, kTbuf);
    k_attn  <<<R_, 256, 0, stream>>>(states, qbuf, kTbuf, wctx, xbuf);
    k_resid <<<R_ / 8, 256, 0, stream>>>(xbuf, ibres, wpT, scT, xb);
    k_out   <<<dim3(V_ / 256, R_ / 64), 256, 0, stream>>>(xb, wb, out);
}